// Round 4
// baseline (103.718 us; speedup 1.0000x reference)
//
#include <hip/hip_runtime.h>
#include <hip/hip_bf16.h>
#include <math.h>

typedef __bf16 bf16x8 __attribute__((ext_vector_type(8)));
typedef __bf16 bf16x4 __attribute__((ext_vector_type(4)));
typedef float  f32x4  __attribute__((ext_vector_type(4)));

#define N_ROWS 4096
#define E_DIM  256
#define BM 128
#define BN 128
#define BK 64
#define NB (2 * N_ROWS / BM)          /* 64 block-rows */
#define LOG2E10 14.426950408889634f   /* 10 * log2(e) */

__device__ __forceinline__ void gload_lds16(const void* g, void* l) {
    __builtin_amdgcn_global_load_lds(
        (const __attribute__((address_space(1))) void*)g,
        (__attribute__((address_space(3))) void*)l,
        16, 0, 0);
}

// ---------------- prep: normalize (1 row/wave) + zero accumulators ----------------
__global__ __launch_bounds__(256) void prep_kernel(
    const float* __restrict__ tab, const float* __restrict__ ts,
    __hip_bfloat16* __restrict__ zn,
    float* __restrict__ rowExp, float* __restrict__ rowPos)
{
    const int tid  = threadIdx.x;
    const int wave = tid >> 6, lane = tid & 63;
    const int row  = blockIdx.x * 4 + wave;

    if (tid < 4) {
        const int r = blockIdx.x * 4 + tid;
        rowExp[r] = 0.f;
        rowPos[r] = 0.f;
    }

    const float* src = row < N_ROWS ? tab + (size_t)row * E_DIM
                                    : ts + (size_t)(row - N_ROWS) * E_DIM;
    const float4 v = *(const float4*)(src + lane * 4);
    float ss = v.x * v.x + v.y * v.y + v.z * v.z + v.w * v.w;
    #pragma unroll
    for (int m = 32; m >= 1; m >>= 1) ss += __shfl_xor(ss, m);
    const float inv = 1.0f / fmaxf(sqrtf(ss), 1e-8f);
    bf16x4 o = { (__bf16)(v.x * inv), (__bf16)(v.y * inv),
                 (__bf16)(v.z * inv), (__bf16)(v.w * inv) };
    *(bf16x4*)(zn + (size_t)row * E_DIM + lane * 4) = o;
}

// ---------------- fused sim GEMM, upper-triangular block grid ----------------
// Tile (i,j), j>=i over 64x64 block grid (2080 blocks). Off-diagonal tiles emit
// BOTH row-sums (rows of rb) and col-sums (rows of cb) -> 2x less GEMM work.
// 128x128 tile, BK=64 single-buffered, global_load_lds(16B), XOR-swizzled chunks.
__global__ __launch_bounds__(256, 4) void simloss_kernel(
    const __hip_bfloat16* __restrict__ zn,
    const int* __restrict__ labels,
    float* __restrict__ rowExp, float* __restrict__ rowPos)
{
    __shared__ __align__(16) char ldsA[BM * BK * 2];  // 16KB
    __shared__ __align__(16) char ldsB[BN * BK * 2];  // 16KB
    __shared__ int labRow[BM];
    __shared__ int labCol[BN];

    // ---- triangular decode: bid -> (i,j), j >= i ----
    const int bid = blockIdx.x;
    int i = (int)((2.0 * NB + 1.0 -
                   sqrt((2.0 * NB + 1.0) * (2.0 * NB + 1.0) - 8.0 * (double)bid)) * 0.5);
    while ((i + 1) * NB - ((i + 1) * i) / 2 <= bid) ++i;
    while (i * NB - (i * (i - 1)) / 2 > bid) --i;
    const int j = i + (bid - (i * NB - (i * (i - 1)) / 2));

    const int rb = i * BM;
    const int cb = j * BM;

    const int tid  = threadIdx.x;
    const int lane = tid & 63;
    const int wave = tid >> 6;
    const int wr = wave >> 1, wc = wave & 1;
    const int l15 = lane & 15, lg = lane >> 4;

    if (tid < BM)      labRow[tid]      = labels[(rb + tid) & (N_ROWS - 1)];
    else               labCol[tid - BM] = labels[(cb + tid - BM) & (N_ROWS - 1)];

    f32x4 acc[4][4];
    #pragma unroll
    for (int a = 0; a < 4; ++a)
        #pragma unroll
        for (int b = 0; b < 4; ++b) acc[a][b] = (f32x4){0.f, 0.f, 0.f, 0.f};

    #pragma unroll
    for (int kt = 0; kt < E_DIM / BK; ++kt) {
        // stage 16KB/matrix: linear LDS dest, pre-swizzled global source
        #pragma unroll
        for (int it = 0; it < 4; ++it) {
            const int idx = it * 256 + wave * 64 + lane;  // 16B chunk id 0..1023
            const int row = idx >> 3;
            const int sch = (idx & 7) ^ (row & 7);
            char* lA = ldsA + (it * 256 + wave * 64) * 16;
            char* lB = ldsB + (it * 256 + wave * 64) * 16;
            gload_lds16(zn + (size_t)(rb + row) * E_DIM + kt * BK + sch * 8, lA);
            gload_lds16(zn + (size_t)(cb + row) * E_DIM + kt * BK + sch * 8, lB);
        }
        __syncthreads();

        #pragma unroll
        for (int ks = 0; ks < 2; ++ks) {
            bf16x8 af[4], bfr[4];
            #pragma unroll
            for (int rf = 0; rf < 4; ++rf) {
                const int r = wr * 64 + rf * 16 + l15;
                af[rf] = *(const bf16x8*)(ldsA + r * 128 + (((ks * 4 + lg) ^ (r & 7)) << 4));
            }
            #pragma unroll
            for (int cf = 0; cf < 4; ++cf) {
                const int c = wc * 64 + cf * 16 + l15;
                bfr[cf] = *(const bf16x8*)(ldsB + c * 128 + (((ks * 4 + lg) ^ (c & 7)) << 4));
            }
            #pragma unroll
            for (int rf = 0; rf < 4; ++rf)
                #pragma unroll
                for (int cf = 0; cf < 4; ++cf)
                    acc[rf][cf] = __builtin_amdgcn_mfma_f32_16x16x32_bf16(af[rf], bfr[cf], acc[rf][cf], 0, 0, 0);
        }
        __syncthreads();
    }

    // ---- epilogue: row-sums always; col-sums when off-diagonal ----
    const bool isDiag = (rb == cb);
    const bool cross  = (rb < N_ROWS) && (cb >= N_ROWS);  // given j>=i

    int cl[4], clab[4];
    #pragma unroll
    for (int cf = 0; cf < 4; ++cf) {
        cl[cf]   = wc * 64 + cf * 16 + l15;
        clab[cf] = labCol[cl[cf]];
    }

    float ecCol[4] = {0.f, 0.f, 0.f, 0.f};
    float pcCol[4] = {0.f, 0.f, 0.f, 0.f};

    #pragma unroll
    for (int rf = 0; rf < 4; ++rf) {
        #pragma unroll
        for (int jj = 0; jj < 4; ++jj) {
            const int rloc = wr * 64 + rf * 16 + lg * 4 + jj;
            const int rlab = labRow[rloc];
            float ep = 0.f, pp = 0.f;
            #pragma unroll
            for (int cf = 0; cf < 4; ++cf) {
                const float s = acc[rf][cf][jj];
                float e = __builtin_amdgcn_exp2f(s * LOG2E10);
                if (isDiag && rloc == cl[cf]) e = 0.f;
                ep += e;
                ecCol[cf] += e;
                if (cross && rlab == clab[cf]) { pp += s; pcCol[cf] += s; }
            }
            #pragma unroll
            for (int m = 1; m <= 8; m <<= 1) {
                ep += __shfl_xor(ep, m);
                if (cross) pp += __shfl_xor(pp, m);
            }
            if (l15 == 0) {
                atomicAdd(&rowExp[rb + rloc], ep);
                if (cross) atomicAdd(&rowPos[rb + rloc], pp);
            }
        }
    }

    if (!isDiag) {
        #pragma unroll
        for (int cf = 0; cf < 4; ++cf) {
            float ec = ecCol[cf], pc = pcCol[cf];
            ec += __shfl_xor(ec, 16); ec += __shfl_xor(ec, 32);
            if (cross) { pc += __shfl_xor(pc, 16); pc += __shfl_xor(pc, 32); }
            if (lg == 0) {
                atomicAdd(&rowExp[cb + cl[cf]], ec);
                if (cross) atomicAdd(&rowPos[cb + cl[cf]], pc);
            }
        }
    }
}

// ---------------- finalize: LDS histogram + per-row logits -> scalar loss ----------------
__global__ __launch_bounds__(256) void finalize_kernel(
    const float* __restrict__ rowExp, const float* __restrict__ rowPos,
    const int* __restrict__ labels, float* __restrict__ out, int N)
{
    __shared__ int hist[256];
    const int twoN = 2 * N;
    const int tid = threadIdx.x;
    hist[tid] = 0;
    __syncthreads();
    for (int idx = tid; idx < N; idx += 256) atomicAdd(&hist[labels[idx]], 1);
    __syncthreads();

    double part = 0.0;
    for (int idx = tid; idx < twoN; idx += 256) {
        const int lab = labels[idx >= N ? idx - N : idx];
        const double mc = 2.0 * (double)hist[lab];
        const double g = ((double)rowPos[idx] * 10.0 - (double)N * log((double)rowExp[idx])) / mc;
        part += g;
    }
    for (int m = 32; m >= 1; m >>= 1) part += __shfl_xor(part, m);
    __shared__ double wsum[4];
    const int wave = tid >> 6, lane = tid & 63;
    if (lane == 0) wsum[wave] = part;
    __syncthreads();
    if (tid == 0) {
        const double tot = wsum[0] + wsum[1] + wsum[2] + wsum[3];
        out[0] = (float)(-tot / (double)twoN);
    }
}

extern "C" void kernel_launch(void* const* d_in, const int* in_sizes, int n_in,
                              void* d_out, int out_size, void* d_ws, size_t ws_size,
                              hipStream_t stream) {
    const float* tab    = (const float*)d_in[0];
    const float* ts     = (const float*)d_in[1];
    const int*   labels = (const int*)d_in[2];
    const int N = in_sizes[2];        // 4096
    const int twoN = 2 * N;

    char* ws = (char*)d_ws;
    __hip_bfloat16* zn = (__hip_bfloat16*)ws;
    const size_t znBytes = (size_t)twoN * E_DIM * sizeof(__hip_bfloat16);
    float* rowExp = (float*)(ws + znBytes);
    float* rowPos = rowExp + twoN;

    prep_kernel<<<twoN / 4, 256, 0, stream>>>(tab, ts, zn, rowExp, rowPos);

    const int nBlocks = NB * (NB + 1) / 2;  // 2080
    simloss_kernel<<<nBlocks, 256, 0, stream>>>(zn, labels, rowExp, rowPos);

    finalize_kernel<<<1, 256, 0, stream>>>(rowExp, rowPos, labels, (float*)d_out, N);
}

// Round 6
// 94.670 us; speedup vs baseline: 1.0956x; 1.0956x over previous
//
#include <hip/hip_runtime.h>
#include <hip/hip_bf16.h>
#include <math.h>

typedef __bf16 bf16x8 __attribute__((ext_vector_type(8)));
typedef __bf16 bf16x4 __attribute__((ext_vector_type(4)));
typedef float  f32x4  __attribute__((ext_vector_type(4)));

#define N_ROWS 4096
#define E_DIM  256
#define TWO_N  (2 * N_ROWS)
#define BM 128
#define BK 64
#define NSB 8                         /* 8 supertile-rows (8x8 blocks each) */
#define LOG2E10 14.426950408889634f   /* 10 * log2(e) */

__device__ __forceinline__ void gload_lds16(const void* g, void* l) {
    __builtin_amdgcn_global_load_lds(
        (const __attribute__((address_space(1))) void*)g,
        (__attribute__((address_space(3))) void*)l,
        16, 0, 0);
}

// ---------------- prep: normalize + bf16 cast, 1 row/wave ----------------
__global__ __launch_bounds__(256) void prep_kernel(
    const float* __restrict__ tab, const float* __restrict__ ts,
    __hip_bfloat16* __restrict__ zn)
{
    const int tid  = threadIdx.x;
    const int wave = tid >> 6, lane = tid & 63;
    const int row  = blockIdx.x * 4 + wave;

    const float* src = row < N_ROWS ? tab + (size_t)row * E_DIM
                                    : ts + (size_t)(row - N_ROWS) * E_DIM;
    const float4 v = *(const float4*)(src + lane * 4);
    float ss = v.x * v.x + v.y * v.y + v.z * v.z + v.w * v.w;
    #pragma unroll
    for (int m = 32; m >= 1; m >>= 1) ss += __shfl_xor(ss, m);
    const float inv = 1.0f / fmaxf(sqrtf(ss), 1e-8f);
    bf16x4 o = { (__bf16)(v.x * inv), (__bf16)(v.y * inv),
                 (__bf16)(v.z * inv), (__bf16)(v.w * inv) };
    *(bf16x4*)(zn + (size_t)row * E_DIM + lane * 4) = o;
}

// ---------------- fused sim GEMM, supertiled upper-triangular grid ----------------
// grid = (64, 36). blockIdx.y -> supertile (I,J), J>=I; blockIdx.x=k ->
// i = 8I+(k&7), j = 8J+(k>>3); j<i (diag supertiles only) exit early.
// Store-only partials, one slot per (block, wave-half):
//   row-side (rows of i): slot 2j+wc  | col-side (rows of j): slot 2i+wr
// -> every slot of rowExpP[128][2N] written exactly once; rowPosP[64][2N] same
//    (view-1 rows row-side, view-2 rows col-side). No atomics, no zero-init.
__global__ __launch_bounds__(256, 4) void simloss_kernel(
    const __hip_bfloat16* __restrict__ zn,
    const int* __restrict__ labels,
    float* __restrict__ rowExpP,   /* [128][8192] */
    float* __restrict__ rowPosP)   /* [64][8192]  */
{
    // ---- supertile decode (integer, cheap) ----
    int y = blockIdx.y, I = 0;
    while (y >= NSB - I) { y -= NSB - I; ++I; }
    const int J = I + y;
    const int k = blockIdx.x;
    const int i = I * 8 + (k & 7);
    const int j = J * 8 + (k >> 3);
    if (j < i) return;  // only inside diagonal supertiles

    const int rb = i * BM;
    const int cb = j * BM;

    __shared__ __align__(16) char ldsA[BM * BK * 2];  // 16KB
    __shared__ __align__(16) char ldsB[BM * BK * 2];  // 16KB
    __shared__ int labRow[BM];
    __shared__ int labCol[BM];

    const int tid  = threadIdx.x;
    const int lane = tid & 63;
    const int wave = tid >> 6;
    const int wr = wave >> 1, wc = wave & 1;
    const int l15 = lane & 15, lg = lane >> 4;

    if (tid < BM)      labRow[tid]      = labels[(rb + tid) & (N_ROWS - 1)];
    else               labCol[tid - BM] = labels[(cb + tid - BM) & (N_ROWS - 1)];

    f32x4 acc[4][4];
    #pragma unroll
    for (int a = 0; a < 4; ++a)
        #pragma unroll
        for (int b = 0; b < 4; ++b) acc[a][b] = (f32x4){0.f, 0.f, 0.f, 0.f};

    #pragma unroll
    for (int kt = 0; kt < E_DIM / BK; ++kt) {
        // stage 16KB/matrix: linear LDS dest, pre-swizzled global source
        #pragma unroll
        for (int it = 0; it < 4; ++it) {
            const int idx = it * 256 + wave * 64 + lane;  // 16B chunk id 0..1023
            const int row = idx >> 3;
            const int sch = (idx & 7) ^ (row & 7);
            char* lA = ldsA + (it * 256 + wave * 64) * 16;
            char* lB = ldsB + (it * 256 + wave * 64) * 16;
            gload_lds16(zn + (size_t)(rb + row) * E_DIM + kt * BK + sch * 8, lA);
            gload_lds16(zn + (size_t)(cb + row) * E_DIM + kt * BK + sch * 8, lB);
        }
        __syncthreads();

        #pragma unroll
        for (int ks = 0; ks < 2; ++ks) {
            bf16x8 af[4], bfr[4];
            #pragma unroll
            for (int rf = 0; rf < 4; ++rf) {
                const int r = wr * 64 + rf * 16 + l15;
                af[rf] = *(const bf16x8*)(ldsA + r * 128 + (((ks * 4 + lg) ^ (r & 7)) << 4));
            }
            #pragma unroll
            for (int cf = 0; cf < 4; ++cf) {
                const int c = wc * 64 + cf * 16 + l15;
                bfr[cf] = *(const bf16x8*)(ldsB + c * 128 + (((ks * 4 + lg) ^ (c & 7)) << 4));
            }
            #pragma unroll
            for (int rf = 0; rf < 4; ++rf)
                #pragma unroll
                for (int cf = 0; cf < 4; ++cf)
                    acc[rf][cf] = __builtin_amdgcn_mfma_f32_16x16x32_bf16(af[rf], bfr[cf], acc[rf][cf], 0, 0, 0);
        }
        __syncthreads();
    }

    // ---- epilogue ----
    const bool isDiag = (i == j);
    const bool cross  = (i < 32) && (j >= 32);

    int cl[4], clab[4];
    #pragma unroll
    for (int cf = 0; cf < 4; ++cf) {
        cl[cf]   = wc * 64 + cf * 16 + l15;
        clab[cf] = labCol[cl[cf]];
    }

    float ecCol[4] = {0.f, 0.f, 0.f, 0.f};
    float pcCol[4] = {0.f, 0.f, 0.f, 0.f};

    // row-side: wave (wr,wc) owns rows rb+wr*64..+63 x cols (wc half) -> slot 2j+wc
    #pragma unroll
    for (int rf = 0; rf < 4; ++rf) {
        #pragma unroll
        for (int jj = 0; jj < 4; ++jj) {
            const int rloc = wr * 64 + rf * 16 + lg * 4 + jj;
            const int rlab = labRow[rloc];
            float ep = 0.f, pp = 0.f;
            #pragma unroll
            for (int cf = 0; cf < 4; ++cf) {
                const float s = acc[rf][cf][jj];
                float e = __builtin_amdgcn_exp2f(s * LOG2E10);
                if (isDiag && rloc == cl[cf]) e = 0.f;
                ep += e;
                ecCol[cf] += e;
                if (cross && rlab == clab[cf]) { pp += s; pcCol[cf] += s; }
            }
            #pragma unroll
            for (int m = 1; m <= 8; m <<= 1) {
                ep += __shfl_xor(ep, m);
                if (cross) pp += __shfl_xor(pp, m);
            }
            if (l15 == 0) {
                rowExpP[(size_t)(2 * j + wc) * TWO_N + rb + rloc] = ep;
                if (cross) rowPosP[(size_t)(2 * (j - 32) + wc) * TWO_N + rb + rloc] = pp;
            }
        }
    }

    // col-side: wave (wr,wc) owns cols cb+wc*64..+63 summed over rows (wr half) -> slot 2i+wr
    if (!isDiag) {
        #pragma unroll
        for (int cf = 0; cf < 4; ++cf) {
            float ec = ecCol[cf], pc = pcCol[cf];
            ec += __shfl_xor(ec, 16); ec += __shfl_xor(ec, 32);
            if (cross) { pc += __shfl_xor(pc, 16); pc += __shfl_xor(pc, 32); }
            if (lg == 0) {
                rowExpP[(size_t)(2 * i + wr) * TWO_N + cb + cl[cf]] = ec;
                if (cross) rowPosP[(size_t)(2 * i + wr) * TWO_N + cb + cl[cf]] = pc;
            }
        }
    }
}

// ---------------- finalize stage 1: reduce partials -> per-block double ----------------
__global__ __launch_bounds__(256) void fin1_kernel(
    const float* __restrict__ rowExpP, const float* __restrict__ rowPosP,
    const int* __restrict__ labels, double* __restrict__ partial)
{
    __shared__ int hist[128];
    const int tid = threadIdx.x;
    if (tid < 128) hist[tid] = 0;
    __syncthreads();
    for (int idx = tid; idx < N_ROWS; idx += 256) atomicAdd(&hist[labels[idx]], 1);
    __syncthreads();

    const int r = blockIdx.x * 256 + tid;  // 0..8191 (grid = 32)
    float es = 0.f;
    #pragma unroll 8
    for (int s = 0; s < 128; ++s) es += rowExpP[(size_t)s * TWO_N + r];
    float ps = 0.f;
    #pragma unroll 8
    for (int s = 0; s < 64; ++s) ps += rowPosP[(size_t)s * TWO_N + r];

    const int lab = labels[r & (N_ROWS - 1)];
    double g = ((double)ps * 10.0 - (double)N_ROWS * log((double)es))
               / (2.0 * (double)hist[lab]);

    #pragma unroll
    for (int m = 32; m >= 1; m >>= 1) g += __shfl_xor(g, m);
    __shared__ double wsum[4];
    const int wave = tid >> 6, lane = tid & 63;
    if (lane == 0) wsum[wave] = g;
    __syncthreads();
    if (tid == 0) partial[blockIdx.x] = wsum[0] + wsum[1] + wsum[2] + wsum[3];
}

// ---------------- finalize stage 2: 32 partials -> scalar ----------------
__global__ void fin2_kernel(const double* __restrict__ partial, float* __restrict__ out) {
    if (threadIdx.x == 0) {
        double tot = 0.0;
        for (int b = 0; b < 32; ++b) tot += partial[b];
        out[0] = (float)(-tot / (double)TWO_N);
    }
}

extern "C" void kernel_launch(void* const* d_in, const int* in_sizes, int n_in,
                              void* d_out, int out_size, void* d_ws, size_t ws_size,
                              hipStream_t stream) {
    const float* tab    = (const float*)d_in[0];
    const float* ts     = (const float*)d_in[1];
    const int*   labels = (const int*)d_in[2];

    char* ws = (char*)d_ws;
    __hip_bfloat16* zn = (__hip_bfloat16*)ws;                        // 4 MB
    const size_t znBytes = (size_t)TWO_N * E_DIM * sizeof(__hip_bfloat16);
    float* rowExpP = (float*)(ws + znBytes);                         // 4 MB [128][8192]
    float* rowPosP = rowExpP + (size_t)128 * TWO_N;                  // 2 MB [64][8192]
    double* partial = (double*)(rowPosP + (size_t)64 * TWO_N);       // 256 B

    prep_kernel<<<TWO_N / 4, 256, 0, stream>>>(tab, ts, zn);

    dim3 grid(64, NSB * (NSB + 1) / 2);  // (64, 36); diag supertiles idle half
    simloss_kernel<<<grid, 256, 0, stream>>>(zn, labels, rowExpP, rowPosP);

    fin1_kernel<<<32, 256, 0, stream>>>(rowExpP, rowPosP, labels, partial);
    fin2_kernel<<<1, 64, 0, stream>>>(partial, (float*)d_out);
}

// Round 7
// 86.725 us; speedup vs baseline: 1.1959x; 1.0916x over previous
//
#include <hip/hip_runtime.h>
#include <hip/hip_bf16.h>
#include <math.h>

typedef __bf16 bf16x8 __attribute__((ext_vector_type(8)));
typedef __bf16 bf16x4 __attribute__((ext_vector_type(4)));
typedef float  f32x4  __attribute__((ext_vector_type(4)));

#define N_ROWS 4096
#define E_DIM  256
#define TWO_N  (2 * N_ROWS)
#define BM 128
#define BK 64
#define LOG2E10 14.426950408889634f   /* 10 * log2(e) */

__device__ __forceinline__ void gload_lds16(const void* g, void* l) {
    __builtin_amdgcn_global_load_lds(
        (const __attribute__((address_space(1))) void*)g,
        (__attribute__((address_space(3))) void*)l,
        16, 0, 0);
}

// ---------------- prep: normalize + bf16 cast, 1 row/wave ----------------
__global__ __launch_bounds__(256) void prep_kernel(
    const float* __restrict__ tab, const float* __restrict__ ts,
    __hip_bfloat16* __restrict__ zn)
{
    const int tid  = threadIdx.x;
    const int wave = tid >> 6, lane = tid & 63;
    const int row  = blockIdx.x * 4 + wave;

    const float* src = row < N_ROWS ? tab + (size_t)row * E_DIM
                                    : ts + (size_t)(row - N_ROWS) * E_DIM;
    const float4 v = *(const float4*)(src + lane * 4);
    float ss = v.x * v.x + v.y * v.y + v.z * v.z + v.w * v.w;
    #pragma unroll
    for (int m = 32; m >= 1; m >>= 1) ss += __shfl_xor(ss, m);
    const float inv = 1.0f / fmaxf(sqrtf(ss), 1e-8f);
    bf16x4 o = { (__bf16)(v.x * inv), (__bf16)(v.y * inv),
                 (__bf16)(v.z * inv), (__bf16)(v.w * inv) };
    *(bf16x4*)(zn + (size_t)row * E_DIM + lane * 4) = o;
}

// ---------------- fused sim GEMM, column-strip upper-triangular grid ----------------
// grid(512, 8): i = x&63 (FAST dim), j = 8*y + (x>>6); exit if i>j.
// XCD = i%8 -> per-XCD A-set fixed {i=c mod 8} (512KB, L2-resident all kernel);
// one shared B panel per (y, x>>6) row -> round-3 locality on the triangle.
// Store-only slot partials (r6-proven ownership):
//   row-side (rows of i): slot 2j+wc | col-side (rows of j): slot 2i+wr
// gathered in LDS, stored as full contiguous 512B runs (no atomics, no sub-line writes).
__global__ __launch_bounds__(256, 4) void simloss_kernel(
    const __hip_bfloat16* __restrict__ zn,
    const int* __restrict__ labels,
    float* __restrict__ rowExpP,   /* [128][8192] */
    float* __restrict__ rowPosP)   /* [64][8192]  */
{
    const int i = blockIdx.x & 63;
    const int j = 8 * blockIdx.y + (blockIdx.x >> 6);
    if (i > j) return;  // lower triangle: idle, instant exit

    const int rb = i * BM;
    const int cb = j * BM;

    __shared__ __align__(16) char ldsA[BM * BK * 2];  // 16KB (reused for epilogue gather)
    __shared__ __align__(16) char ldsB[BM * BK * 2];  // 16KB
    __shared__ int labRow[BM];
    __shared__ int labCol[BM];

    const int tid  = threadIdx.x;
    const int lane = tid & 63;
    const int wave = tid >> 6;
    const int wr = wave >> 1, wc = wave & 1;
    const int l15 = lane & 15, lg = lane >> 4;

    if (tid < BM)      labRow[tid]      = labels[(rb + tid) & (N_ROWS - 1)];
    else               labCol[tid - BM] = labels[(cb + tid - BM) & (N_ROWS - 1)];

    f32x4 acc[4][4];
    #pragma unroll
    for (int a = 0; a < 4; ++a)
        #pragma unroll
        for (int b = 0; b < 4; ++b) acc[a][b] = (f32x4){0.f, 0.f, 0.f, 0.f};

    #pragma unroll
    for (int kt = 0; kt < E_DIM / BK; ++kt) {
        // stage 16KB/matrix: linear LDS dest, pre-swizzled global source
        #pragma unroll
        for (int it = 0; it < 4; ++it) {
            const int idx = it * 256 + wave * 64 + lane;  // 16B chunk id 0..1023
            const int row = idx >> 3;
            const int sch = (idx & 7) ^ (row & 7);
            char* lA = ldsA + (it * 256 + wave * 64) * 16;
            char* lB = ldsB + (it * 256 + wave * 64) * 16;
            gload_lds16(zn + (size_t)(rb + row) * E_DIM + kt * BK + sch * 8, lA);
            gload_lds16(zn + (size_t)(cb + row) * E_DIM + kt * BK + sch * 8, lB);
        }
        __syncthreads();

        #pragma unroll
        for (int ks = 0; ks < 2; ++ks) {
            bf16x8 af[4], bfr[4];
            #pragma unroll
            for (int rf = 0; rf < 4; ++rf) {
                const int r = wr * 64 + rf * 16 + l15;
                af[rf] = *(const bf16x8*)(ldsA + r * 128 + (((ks * 4 + lg) ^ (r & 7)) << 4));
            }
            #pragma unroll
            for (int cf = 0; cf < 4; ++cf) {
                const int c = wc * 64 + cf * 16 + l15;
                bfr[cf] = *(const bf16x8*)(ldsB + c * 128 + (((ks * 4 + lg) ^ (c & 7)) << 4));
            }
            #pragma unroll
            for (int rf = 0; rf < 4; ++rf)
                #pragma unroll
                for (int cf = 0; cf < 4; ++cf)
                    acc[rf][cf] = __builtin_amdgcn_mfma_f32_16x16x32_bf16(af[rf], bfr[cf], acc[rf][cf], 0, 0, 0);
        }
        __syncthreads();
    }

    // ---- epilogue: reduce, gather in LDS, coalesced full-line stores ----
    const bool isDiag = (i == j);
    const bool cross  = (i < 32) && (j >= 32);

    float* shRE = (float*)ldsA;        // [2][128] row-side exp   (wc half)
    float* shCE = shRE + 256;          // [2][128] col-side exp   (wr half)
    float* shRP = shCE + 256;          // [2][128] row-side pos
    float* shCP = shRP + 256;          // [2][128] col-side pos

    int cl[4], clab[4];
    #pragma unroll
    for (int cf = 0; cf < 4; ++cf) {
        cl[cf]   = wc * 64 + cf * 16 + l15;
        clab[cf] = labCol[cl[cf]];
    }

    float ecCol[4] = {0.f, 0.f, 0.f, 0.f};
    float pcCol[4] = {0.f, 0.f, 0.f, 0.f};

    #pragma unroll
    for (int rf = 0; rf < 4; ++rf) {
        #pragma unroll
        for (int jj = 0; jj < 4; ++jj) {
            const int rloc = wr * 64 + rf * 16 + lg * 4 + jj;
            const int rlab = labRow[rloc];
            float ep = 0.f, pp = 0.f;
            #pragma unroll
            for (int cf = 0; cf < 4; ++cf) {
                const float s = acc[rf][cf][jj];
                float e = __builtin_amdgcn_exp2f(s * LOG2E10);
                if (isDiag && rloc == cl[cf]) e = 0.f;
                ep += e;
                ecCol[cf] += e;
                if (cross && rlab == clab[cf]) { pp += s; pcCol[cf] += s; }
            }
            #pragma unroll
            for (int m = 1; m <= 8; m <<= 1) {
                ep += __shfl_xor(ep, m);
                if (cross) pp += __shfl_xor(pp, m);
            }
            if (l15 == 0) {
                shRE[wc * 128 + rloc] = ep;
                if (cross) shRP[wc * 128 + rloc] = pp;
            }
        }
    }

    #pragma unroll
    for (int cf = 0; cf < 4; ++cf) {
        float ec = ecCol[cf], pc = pcCol[cf];
        ec += __shfl_xor(ec, 16); ec += __shfl_xor(ec, 32);
        if (cross) { pc += __shfl_xor(pc, 16); pc += __shfl_xor(pc, 32); }
        if (lg == 0) {
            shCE[wr * 128 + cl[cf]] = ec;
            if (cross) shCP[wr * 128 + cl[cf]] = pc;
        }
    }

    __syncthreads();

    const int half = tid >> 7;          // 0/1 -> slot half
    const int r128 = tid & 127;
    rowExpP[(size_t)(2 * j + half) * TWO_N + rb + r128] = shRE[tid];
    if (!isDiag)
        rowExpP[(size_t)(2 * i + half) * TWO_N + cb + r128] = shCE[tid];
    if (cross) {
        rowPosP[(size_t)(2 * (j - 32) + half) * TWO_N + rb + r128] = shRP[tid];
        rowPosP[(size_t)(2 * i + half) * TWO_N + cb + r128]        = shCP[tid];
    }
}

// ---------------- finalize stage 1: reduce partials -> per-block double ----------------
__global__ __launch_bounds__(256) void fin1_kernel(
    const float* __restrict__ rowExpP, const float* __restrict__ rowPosP,
    const int* __restrict__ labels, double* __restrict__ partial)
{
    __shared__ int hist[128];
    const int tid = threadIdx.x;
    if (tid < 128) hist[tid] = 0;
    __syncthreads();
    for (int idx = tid; idx < N_ROWS; idx += 256) atomicAdd(&hist[labels[idx]], 1);
    __syncthreads();

    const int r = blockIdx.x * 256 + tid;  // 0..8191 (grid = 32)
    float es = 0.f;
    #pragma unroll 8
    for (int s = 0; s < 128; ++s) es += rowExpP[(size_t)s * TWO_N + r];
    float ps = 0.f;
    #pragma unroll 8
    for (int s = 0; s < 64; ++s) ps += rowPosP[(size_t)s * TWO_N + r];

    const int lab = labels[r & (N_ROWS - 1)];
    double g = ((double)ps * 10.0 - (double)N_ROWS * log((double)es))
               / (2.0 * (double)hist[lab]);

    #pragma unroll
    for (int m = 32; m >= 1; m >>= 1) g += __shfl_xor(g, m);
    __shared__ double wsum[4];
    const int wave = tid >> 6, lane = tid & 63;
    if (lane == 0) wsum[wave] = g;
    __syncthreads();
    if (tid == 0) partial[blockIdx.x] = wsum[0] + wsum[1] + wsum[2] + wsum[3];
}

// ---------------- finalize stage 2: 32 partials -> scalar ----------------
__global__ void fin2_kernel(const double* __restrict__ partial, float* __restrict__ out) {
    if (threadIdx.x == 0) {
        double tot = 0.0;
        for (int b = 0; b < 32; ++b) tot += partial[b];
        out[0] = (float)(-tot / (double)TWO_N);
    }
}

extern "C" void kernel_launch(void* const* d_in, const int* in_sizes, int n_in,
                              void* d_out, int out_size, void* d_ws, size_t ws_size,
                              hipStream_t stream) {
    const float* tab    = (const float*)d_in[0];
    const float* ts     = (const float*)d_in[1];
    const int*   labels = (const int*)d_in[2];

    char* ws = (char*)d_ws;
    __hip_bfloat16* zn = (__hip_bfloat16*)ws;                        // 4 MB
    const size_t znBytes = (size_t)TWO_N * E_DIM * sizeof(__hip_bfloat16);
    float* rowExpP = (float*)(ws + znBytes);                         // 4 MB [128][8192]
    float* rowPosP = rowExpP + (size_t)128 * TWO_N;                  // 2 MB [64][8192]
    double* partial = (double*)(rowPosP + (size_t)64 * TWO_N);       // 256 B

    prep_kernel<<<TWO_N / 4, 256, 0, stream>>>(tab, ts, zn);

    dim3 grid(512, 8);  // i = x&63 fast, j = 8y + (x>>6); lower-triangle blocks exit
    simloss_kernel<<<grid, 256, 0, stream>>>(zn, labels, rowExpP, rowPosP);

    fin1_kernel<<<32, 256, 0, stream>>>(rowExpP, rowPosP, labels, partial);
    fin2_kernel<<<1, 64, 0, stream>>>(partial, (float*)d_out);
}

// Round 8
// 82.019 us; speedup vs baseline: 1.2646x; 1.0574x over previous
//
#include <hip/hip_runtime.h>
#include <hip/hip_bf16.h>
#include <math.h>

typedef __bf16 bf16x8 __attribute__((ext_vector_type(8)));
typedef __bf16 bf16x4 __attribute__((ext_vector_type(4)));
typedef float  f32x4  __attribute__((ext_vector_type(4)));

#define N_ROWS 4096
#define E_DIM  256
#define TWO_N  (2 * N_ROWS)
#define BM 128
#define BK 64
#define LOG2E10 14.426950408889634f   /* 10 * log2(e) */

__device__ __forceinline__ void gload_lds16(const void* g, void* l) {
    __builtin_amdgcn_global_load_lds(
        (const __attribute__((address_space(1))) void*)g,
        (__attribute__((address_space(3))) void*)l,
        16, 0, 0);
}

// ---------------- prep: normalize + bf16 cast, 1 row/wave ----------------
__global__ __launch_bounds__(256) void prep_kernel(
    const float* __restrict__ tab, const float* __restrict__ ts,
    __hip_bfloat16* __restrict__ zn)
{
    const int tid  = threadIdx.x;
    const int wave = tid >> 6, lane = tid & 63;
    const int row  = blockIdx.x * 4 + wave;

    const float* src = row < N_ROWS ? tab + (size_t)row * E_DIM
                                    : ts + (size_t)(row - N_ROWS) * E_DIM;
    const float4 v = *(const float4*)(src + lane * 4);
    float ss = v.x * v.x + v.y * v.y + v.z * v.z + v.w * v.w;
    #pragma unroll
    for (int m = 32; m >= 1; m >>= 1) ss += __shfl_xor(ss, m);
    const float inv = 1.0f / fmaxf(sqrtf(ss), 1e-8f);
    bf16x4 o = { (__bf16)(v.x * inv), (__bf16)(v.y * inv),
                 (__bf16)(v.z * inv), (__bf16)(v.w * inv) };
    *(bf16x4*)(zn + (size_t)row * E_DIM + lane * 4) = o;
}

// ---------------- fused sim GEMM, FULL grid (r3 locality), store-partial epilogue ----------------
// grid(64,64): i = blockIdx.x (fast), j = blockIdx.y. XCD = i%8 -> fixed 512KB A-set
// per XCD (L2-resident), one shared B panel per j-strip. 14 ns/tile proven (r3).
// Row-side-only partials, one slot per (block, wc-half): rowExpP slot 2j+half;
// cross blocks also rowPosP slot 2*(j%32)+half. Every slot written exactly once:
// no atomics, no zero-init. LDS-gathered -> full 512B coalesced runs.
__global__ __launch_bounds__(256, 4) void simloss_kernel(
    const __hip_bfloat16* __restrict__ zn,
    const int* __restrict__ labels,
    float* __restrict__ rowExpP,   /* [128][8192] */
    float* __restrict__ rowPosP)   /* [64][8192]  */
{
    const int i = blockIdx.x;
    const int j = blockIdx.y;

    const int rb = i * BM;
    const int cb = j * BM;

    __shared__ __align__(16) char ldsA[BM * BK * 2];  // 16KB (reused for epilogue gather)
    __shared__ __align__(16) char ldsB[BM * BK * 2];  // 16KB
    __shared__ int labRow[BM];
    __shared__ int labCol[BM];

    const int tid  = threadIdx.x;
    const int lane = tid & 63;
    const int wave = tid >> 6;
    const int wr = wave >> 1, wc = wave & 1;
    const int l15 = lane & 15, lg = lane >> 4;

    if (tid < BM)      labRow[tid]      = labels[(rb + tid) & (N_ROWS - 1)];
    else               labCol[tid - BM] = labels[(cb + tid - BM) & (N_ROWS - 1)];

    f32x4 acc[4][4];
    #pragma unroll
    for (int a = 0; a < 4; ++a)
        #pragma unroll
        for (int b = 0; b < 4; ++b) acc[a][b] = (f32x4){0.f, 0.f, 0.f, 0.f};

    #pragma unroll
    for (int kt = 0; kt < E_DIM / BK; ++kt) {
        // stage 16KB/matrix: linear LDS dest, pre-swizzled global source
        #pragma unroll
        for (int it = 0; it < 4; ++it) {
            const int idx = it * 256 + wave * 64 + lane;  // 16B chunk id 0..1023
            const int row = idx >> 3;
            const int sch = (idx & 7) ^ (row & 7);
            char* lA = ldsA + (it * 256 + wave * 64) * 16;
            char* lB = ldsB + (it * 256 + wave * 64) * 16;
            gload_lds16(zn + (size_t)(rb + row) * E_DIM + kt * BK + sch * 8, lA);
            gload_lds16(zn + (size_t)(cb + row) * E_DIM + kt * BK + sch * 8, lB);
        }
        __syncthreads();

        #pragma unroll
        for (int ks = 0; ks < 2; ++ks) {
            bf16x8 af[4], bfr[4];
            #pragma unroll
            for (int rf = 0; rf < 4; ++rf) {
                const int r = wr * 64 + rf * 16 + l15;
                af[rf] = *(const bf16x8*)(ldsA + r * 128 + (((ks * 4 + lg) ^ (r & 7)) << 4));
            }
            #pragma unroll
            for (int cf = 0; cf < 4; ++cf) {
                const int c = wc * 64 + cf * 16 + l15;
                bfr[cf] = *(const bf16x8*)(ldsB + c * 128 + (((ks * 4 + lg) ^ (c & 7)) << 4));
            }
            #pragma unroll
            for (int rf = 0; rf < 4; ++rf)
                #pragma unroll
                for (int cf = 0; cf < 4; ++cf)
                    acc[rf][cf] = __builtin_amdgcn_mfma_f32_16x16x32_bf16(af[rf], bfr[cf], acc[rf][cf], 0, 0, 0);
        }
        __syncthreads();
    }

    // ---- epilogue: reduce row-side, gather in LDS, coalesced full-line stores ----
    const bool isDiag = (i == j);
    const bool cross  = (i < 32) != (j < 32);

    float* shRE = (float*)ldsA;        // [2][128] row-side exp (wc half)
    float* shRP = shRE + 256;          // [2][128] row-side pos

    int cl[4], clab[4];
    #pragma unroll
    for (int cf = 0; cf < 4; ++cf) {
        cl[cf]   = wc * 64 + cf * 16 + l15;
        clab[cf] = labCol[cl[cf]];
    }

    #pragma unroll
    for (int rf = 0; rf < 4; ++rf) {
        #pragma unroll
        for (int jj = 0; jj < 4; ++jj) {
            const int rloc = wr * 64 + rf * 16 + lg * 4 + jj;
            const int rlab = labRow[rloc];
            float ep = 0.f, pp = 0.f;
            #pragma unroll
            for (int cf = 0; cf < 4; ++cf) {
                const float s = acc[rf][cf][jj];
                float e = __builtin_amdgcn_exp2f(s * LOG2E10);
                if (isDiag && rloc == cl[cf]) e = 0.f;
                ep += e;
                if (cross && rlab == clab[cf]) pp += s;
            }
            #pragma unroll
            for (int m = 1; m <= 8; m <<= 1) {
                ep += __shfl_xor(ep, m);
                if (cross) pp += __shfl_xor(pp, m);
            }
            if (l15 == 0) {
                shRE[wc * 128 + rloc] = ep;
                if (cross) shRP[wc * 128 + rloc] = pp;
            }
        }
    }

    __syncthreads();

    const int half = tid >> 7;          // 0/1 -> slot half
    const int r128 = tid & 127;
    rowExpP[(size_t)(2 * j + half) * TWO_N + rb + r128] = shRE[tid];
    if (cross) {
        const int jm = (j < 32) ? j : j - 32;
        rowPosP[(size_t)(2 * jm + half) * TWO_N + rb + r128] = shRP[tid];
    }
}

// ---------------- finalize stage 1: reduce partials -> per-block double ----------------
__global__ __launch_bounds__(256) void fin1_kernel(
    const float* __restrict__ rowExpP, const float* __restrict__ rowPosP,
    const int* __restrict__ labels, double* __restrict__ partial)
{
    __shared__ int hist[128];
    const int tid = threadIdx.x;
    if (tid < 128) hist[tid] = 0;
    __syncthreads();
    for (int idx = tid; idx < N_ROWS; idx += 256) atomicAdd(&hist[labels[idx]], 1);
    __syncthreads();

    const int r = blockIdx.x * 256 + tid;  // 0..8191 (grid = 32)
    float es = 0.f;
    #pragma unroll 8
    for (int s = 0; s < 128; ++s) es += rowExpP[(size_t)s * TWO_N + r];
    float ps = 0.f;
    #pragma unroll 8
    for (int s = 0; s < 64; ++s) ps += rowPosP[(size_t)s * TWO_N + r];

    const int lab = labels[r & (N_ROWS - 1)];
    double g = ((double)ps * 10.0 - (double)N_ROWS * log((double)es))
               / (2.0 * (double)hist[lab]);

    #pragma unroll
    for (int m = 32; m >= 1; m >>= 1) g += __shfl_xor(g, m);
    __shared__ double wsum[4];
    const int wave = tid >> 6, lane = tid & 63;
    if (lane == 0) wsum[wave] = g;
    __syncthreads();
    if (tid == 0) partial[blockIdx.x] = wsum[0] + wsum[1] + wsum[2] + wsum[3];
}

// ---------------- finalize stage 2: 32 partials -> scalar ----------------
__global__ void fin2_kernel(const double* __restrict__ partial, float* __restrict__ out) {
    if (threadIdx.x == 0) {
        double tot = 0.0;
        for (int b = 0; b < 32; ++b) tot += partial[b];
        out[0] = (float)(-tot / (double)TWO_N);
    }
}

extern "C" void kernel_launch(void* const* d_in, const int* in_sizes, int n_in,
                              void* d_out, int out_size, void* d_ws, size_t ws_size,
                              hipStream_t stream) {
    const float* tab    = (const float*)d_in[0];
    const float* ts     = (const float*)d_in[1];
    const int*   labels = (const int*)d_in[2];

    char* ws = (char*)d_ws;
    __hip_bfloat16* zn = (__hip_bfloat16*)ws;                        // 4 MB
    const size_t znBytes = (size_t)TWO_N * E_DIM * sizeof(__hip_bfloat16);
    float* rowExpP = (float*)(ws + znBytes);                         // 4 MB [128][8192]
    float* rowPosP = rowExpP + (size_t)128 * TWO_N;                  // 2 MB [64][8192]
    double* partial = (double*)(rowPosP + (size_t)64 * TWO_N);       // 256 B

    prep_kernel<<<TWO_N / 4, 256, 0, stream>>>(tab, ts, zn);

    dim3 grid(64, 64);  // full grid, i fast: XCD = i%8, r3-proven locality
    simloss_kernel<<<grid, 256, 0, stream>>>(zn, labels, rowExpP, rowPosP);

    fin1_kernel<<<32, 256, 0, stream>>>(rowExpP, rowPosP, labels, partial);
    fin2_kernel<<<1, 64, 0, stream>>>(partial, (float*)d_out);
}

// Round 9
// 80.061 us; speedup vs baseline: 1.2955x; 1.0245x over previous
//
#include <hip/hip_runtime.h>
#include <hip/hip_bf16.h>
#include <math.h>

typedef __bf16 bf16x8 __attribute__((ext_vector_type(8)));
typedef __bf16 bf16x4 __attribute__((ext_vector_type(4)));
typedef float  f32x4  __attribute__((ext_vector_type(4)));

#define N_ROWS 4096
#define E_DIM  256
#define TWO_N  (2 * N_ROWS)
#define BM 256                        /* rows per block  */
#define BN 128                        /* cols per block  */
#define BK 64
#define LOG2E10 14.426950408889634f   /* 10 * log2(e) */
#define SQRT_L 3.798282567081813f     /* sqrt(LOG2E10): folded into zn so acc = s*LOG2E10 */

__device__ __forceinline__ void gload_lds16(const void* g, void* l) {
    __builtin_amdgcn_global_load_lds(
        (const __attribute__((address_space(1))) void*)g,
        (__attribute__((address_space(3))) void*)l,
        16, 0, 0);
}

// ---------------- prep: normalize + fold sqrt(10*log2e) + bf16 cast ----------------
__global__ __launch_bounds__(256) void prep_kernel(
    const float* __restrict__ tab, const float* __restrict__ ts,
    __hip_bfloat16* __restrict__ zn)
{
    const int tid  = threadIdx.x;
    const int wave = tid >> 6, lane = tid & 63;
    const int row  = blockIdx.x * 4 + wave;

    const float* src = row < N_ROWS ? tab + (size_t)row * E_DIM
                                    : ts + (size_t)(row - N_ROWS) * E_DIM;
    const float4 v = *(const float4*)(src + lane * 4);
    float ss = v.x * v.x + v.y * v.y + v.z * v.z + v.w * v.w;
    #pragma unroll
    for (int m = 32; m >= 1; m >>= 1) ss += __shfl_xor(ss, m);
    const float inv = SQRT_L / fmaxf(sqrtf(ss), 1e-8f);
    bf16x4 o = { (__bf16)(v.x * inv), (__bf16)(v.y * inv),
                 (__bf16)(v.z * inv), (__bf16)(v.w * inv) };
    *(bf16x4*)(zn + (size_t)row * E_DIM + lane * 4) = o;
}

// ---------------- fused sim GEMM: 256x128 tile, 8 waves, store-partial epilogue ----------------
// grid(32,64): i = blockIdx.x (fast, XCD = i%8 -> fixed 512KB A-set/XCD),
// j = blockIdx.y (one shared B panel per j-strip).
// acc = sim * LOG2E10 (scale folded into zn). Epilogue exp = exp2(acc), no mul.
// Row-side partials, unique slot per (block, col-half): rowExpP slot 2j+half;
// cross blocks also rowPosP slot 2*(j%32)+half (scaled; fin1 multiplies by ln2).
__global__ __launch_bounds__(512, 4) void simloss_kernel(
    const __hip_bfloat16* __restrict__ zn,
    const int* __restrict__ labels,
    float* __restrict__ rowExpP,   /* [128][8192] */
    float* __restrict__ rowPosP)   /* [64][8192]  */
{
    const int i = blockIdx.x;      // 0..31 (256-row panel)
    const int j = blockIdx.y;      // 0..63 (128-col panel)

    const int rb = i * BM;
    const int cb = j * BN;

    __shared__ __align__(16) char ldsA[BM * BK * 2];  // 32KB (reused for epilogue gather)
    __shared__ __align__(16) char ldsB[BN * BK * 2];  // 16KB
    __shared__ int labRow[BM];
    __shared__ int labCol[BN];

    const int tid  = threadIdx.x;
    const int lane = tid & 63;
    const int wave = tid >> 6;           // 0..7
    const int wr = wave >> 1, wc = wave & 1;
    const int l15 = lane & 15, lg = lane >> 4;

    if (tid < BM)           labRow[tid]       = labels[(rb + tid) & (N_ROWS - 1)];
    else if (tid < BM + BN) labCol[tid - BM]  = labels[(cb + tid - BM) & (N_ROWS - 1)];

    f32x4 acc[4][4];
    #pragma unroll
    for (int a = 0; a < 4; ++a)
        #pragma unroll
        for (int b = 0; b < 4; ++b) acc[a][b] = (f32x4){0.f, 0.f, 0.f, 0.f};

    #pragma unroll
    for (int kt = 0; kt < E_DIM / BK; ++kt) {
        // stage A: 32KB = 2048 chunks, 4 its; B: 16KB = 1024 chunks, 2 its.
        // linear LDS dest (wave-uniform base), pre-swizzled global source chunk.
        #pragma unroll
        for (int it = 0; it < 4; ++it) {
            const int idx = it * 512 + wave * 64 + lane;   // 0..2047
            const int row = idx >> 3;                      // 0..255
            const int sch = (idx & 7) ^ (row & 7);
            gload_lds16(zn + (size_t)(rb + row) * E_DIM + kt * BK + sch * 8,
                        ldsA + (it * 512 + wave * 64) * 16);
        }
        #pragma unroll
        for (int it = 0; it < 2; ++it) {
            const int idx = it * 512 + wave * 64 + lane;   // 0..1023
            const int row = idx >> 3;                      // 0..127
            const int sch = (idx & 7) ^ (row & 7);
            gload_lds16(zn + (size_t)(cb + row) * E_DIM + kt * BK + sch * 8,
                        ldsB + (it * 512 + wave * 64) * 16);
        }
        __syncthreads();

        #pragma unroll
        for (int ks = 0; ks < 2; ++ks) {
            bf16x8 af[4], bfr[4];
            #pragma unroll
            for (int rf = 0; rf < 4; ++rf) {
                const int r = wr * 64 + rf * 16 + l15;     // 0..255
                af[rf] = *(const bf16x8*)(ldsA + r * 128 + (((ks * 4 + lg) ^ (r & 7)) << 4));
            }
            #pragma unroll
            for (int cf = 0; cf < 4; ++cf) {
                const int c = wc * 64 + cf * 16 + l15;     // 0..127
                bfr[cf] = *(const bf16x8*)(ldsB + c * 128 + (((ks * 4 + lg) ^ (c & 7)) << 4));
            }
            #pragma unroll
            for (int rf = 0; rf < 4; ++rf)
                #pragma unroll
                for (int cf = 0; cf < 4; ++cf)
                    acc[rf][cf] = __builtin_amdgcn_mfma_f32_16x16x32_bf16(af[rf], bfr[cf], acc[rf][cf], 0, 0, 0);
        }
        __syncthreads();
    }

    // ---- epilogue: row-reduce, LDS-gather, coalesced full-line stores ----
    const bool isDiag = (i == (j >> 1));               // this block touches the diagonal
    const bool cross  = (i < 16) != (j < 32);

    float* shRE = (float*)ldsA;        // [2][256] row-side exp (wc half)
    float* shRP = shRE + 512;          // [2][256] row-side pos

    int gcol[4], clab[4];
    #pragma unroll
    for (int cf = 0; cf < 4; ++cf) {
        const int cl = wc * 64 + cf * 16 + l15;
        gcol[cf] = cb + cl;
        clab[cf] = labCol[cl];
    }

    #pragma unroll
    for (int rf = 0; rf < 4; ++rf) {
        #pragma unroll
        for (int jj = 0; jj < 4; ++jj) {
            const int rloc = wr * 64 + rf * 16 + lg * 4 + jj;   // 0..255
            const int grow = rb + rloc;
            const int rlab = labRow[rloc];
            float ep = 0.f, pp = 0.f;
            #pragma unroll
            for (int cf = 0; cf < 4; ++cf) {
                const float s = acc[rf][cf][jj];                // = sim * LOG2E10
                float e = __builtin_amdgcn_exp2f(s);            // no mul: scale folded
                if (isDiag && grow == gcol[cf]) e = 0.f;
                ep += e;
                if (cross && rlab == clab[cf]) pp += s;
            }
            #pragma unroll
            for (int m = 1; m <= 8; m <<= 1) {
                ep += __shfl_xor(ep, m);
                if (cross) pp += __shfl_xor(pp, m);
            }
            if (l15 == 0) {
                shRE[wc * 256 + rloc] = ep;
                if (cross) shRP[wc * 256 + rloc] = pp;
            }
        }
    }

    __syncthreads();

    const int half = tid >> 8;          // 0/1 -> col-half slot
    const int r = tid & 255;
    rowExpP[(size_t)(2 * j + half) * TWO_N + rb + r] = shRE[tid];
    if (cross) {
        const int jm = (j < 32) ? j : j - 32;
        rowPosP[(size_t)(2 * jm + half) * TWO_N + rb + r] = shRP[tid];
    }
}

// ---------------- finalize stage 1: reduce partials -> per-block double ----------------
__global__ __launch_bounds__(256) void fin1_kernel(
    const float* __restrict__ rowExpP, const float* __restrict__ rowPosP,
    const int* __restrict__ labels, double* __restrict__ partial)
{
    __shared__ int hist[128];
    const int tid = threadIdx.x;
    if (tid < 128) hist[tid] = 0;
    __syncthreads();
    for (int idx = tid; idx < N_ROWS; idx += 256) atomicAdd(&hist[labels[idx]], 1);
    __syncthreads();

    const int r = blockIdx.x * 256 + tid;  // 0..8191 (grid = 32)
    float es = 0.f;
    #pragma unroll 8
    for (int s = 0; s < 128; ++s) es += rowExpP[(size_t)s * TWO_N + r];
    float ps = 0.f;
    #pragma unroll 8
    for (int s = 0; s < 64; ++s) ps += rowPosP[(size_t)s * TWO_N + r];

    const int lab = labels[r & (N_ROWS - 1)];
    // ps is scaled by LOG2E10; 10*sim_sum = ps * ln(2)
    double g = ((double)ps * 0.6931471805599453 - (double)N_ROWS * log((double)es))
               / (2.0 * (double)hist[lab]);

    #pragma unroll
    for (int m = 32; m >= 1; m >>= 1) g += __shfl_xor(g, m);
    __shared__ double wsum[4];
    const int wave = tid >> 6, lane = tid & 63;
    if (lane == 0) wsum[wave] = g;
    __syncthreads();
    if (tid == 0) partial[blockIdx.x] = wsum[0] + wsum[1] + wsum[2] + wsum[3];
}

// ---------------- finalize stage 2: 32 partials -> scalar ----------------
__global__ void fin2_kernel(const double* __restrict__ partial, float* __restrict__ out) {
    if (threadIdx.x == 0) {
        double tot = 0.0;
        for (int b = 0; b < 32; ++b) tot += partial[b];
        out[0] = (float)(-tot / (double)TWO_N);
    }
}

extern "C" void kernel_launch(void* const* d_in, const int* in_sizes, int n_in,
                              void* d_out, int out_size, void* d_ws, size_t ws_size,
                              hipStream_t stream) {
    const float* tab    = (const float*)d_in[0];
    const float* ts     = (const float*)d_in[1];
    const int*   labels = (const int*)d_in[2];

    char* ws = (char*)d_ws;
    __hip_bfloat16* zn = (__hip_bfloat16*)ws;                        // 4 MB
    const size_t znBytes = (size_t)TWO_N * E_DIM * sizeof(__hip_bfloat16);
    float* rowExpP = (float*)(ws + znBytes);                         // 4 MB [128][8192]
    float* rowPosP = rowExpP + (size_t)128 * TWO_N;                  // 2 MB [64][8192]
    double* partial = (double*)(rowPosP + (size_t)64 * TWO_N);       // 256 B

    prep_kernel<<<TWO_N / 4, 256, 0, stream>>>(tab, ts, zn);

    dim3 grid(32, 64);  // i fast (XCD = i%8), 256x128 tiles
    simloss_kernel<<<grid, 512, 0, stream>>>(zn, labels, rowExpP, rowPosP);

    fin1_kernel<<<32, 256, 0, stream>>>(rowExpP, rowPosP, labels, partial);
    fin2_kernel<<<1, 64, 0, stream>>>(partial, (float*)d_out);
}